// Round 10
// baseline (330.018 us; speedup 1.0000x reference)
//
#include <hip/hip_runtime.h>

// GCN 2-layer (R10) — DIAGNOSTIC ROUND. Base = R7 (best, 179.4us), with each
// idempotent kernel body repeated reps x (K1-gemm x3, K2 x6, K3 x3, K4 x3;
// P1 scatter runs once) so every real kernel exceeds the 41.6us fill floor
// and lands in the top-5 WITH counters. Output identical (bodies idempotent;
// pstride=0 pointer perturbation defeats cross-rep CSE). dur/reps = true
// per-kernel time. Expected total ~300-400us THIS ROUND ONLY.
// K0 clear+wprep -> K1 [P1-bucket | gemm1 x3] -> K2 CSR x6 ->
// K3 agg128+gemm2 x3 -> K4 agg64 x3 -> d_out.

#define TPB 256
#define NBKT 196        // ceil(50000/256) buckets of 256 nodes
#define EB_CAP 4608     // edge-buffer slots per bucket (mean 4096 + 8 sigma)
#define CSR_CAP 6400    // 4608 + 256*7 pad-to-8 worst case
#define P1_EPB 4096     // edges per P1 block (16 KB sPacked)

typedef __bf16 bf16x8 __attribute__((ext_vector_type(8)));
typedef __bf16 bf16x4 __attribute__((ext_vector_type(4)));
typedef __bf16 bf16x2 __attribute__((ext_vector_type(2)));
typedef float f32x4 __attribute__((ext_vector_type(4)));

__device__ __forceinline__ float bflo(unsigned u) { return __uint_as_float(u << 16); }
__device__ __forceinline__ float bfhi(unsigned u) { return __uint_as_float(u & 0xffff0000u); }

// ---------------- K0: clear gcnt, zero sentinel rows, W frag pack ----------------
__global__ __launch_bounds__(256) void clear_wprep_kernel(
    unsigned* __restrict__ gcnt, float* __restrict__ dinv, __bf16* __restrict__ h2s,
    int N,
    const float* __restrict__ W1, const float* __restrict__ W2,
    __bf16* __restrict__ wf1, __bf16* __restrict__ wf2) {
    if (blockIdx.x == 0) {
        int t = threadIdx.x;
        if (t < NBKT) gcnt[t] = 0;
        if (t == 0) dinv[N] = 0.0f;                       // sentinel weight
        if (t < 32) ((unsigned*)(h2s + (long)N * 64))[t] = 0u;  // sentinel row = 0
        return;
    }
    int g = (blockIdx.x - 1) * TPB + threadIdx.x;
    if (g < 64 * 64) {  // W1: K=256 (8 ksteps), OC=128 (8 octiles)
        int frag = g >> 6, L = g & 63;
        int kstep = frag >> 3, oct = frag & 7;
        int oc = oct * 16 + (L & 15);
        int k0 = kstep * 32 + (L >> 4) * 8;
        bf16x8 v;
#pragma unroll
        for (int j = 0; j < 8; j++) v[j] = (__bf16)W1[(k0 + j) * 128 + oc];
        ((bf16x8*)wf1)[g] = v;
    } else if (g < 64 * 64 + 16 * 64) {  // W2: K=128 (4), OC=64 (4)
        int g2 = g - 64 * 64;
        int frag = g2 >> 6, L = g2 & 63;
        int kstep = frag >> 2, oct = frag & 3;
        int oc = oct * 16 + (L & 15);
        int k0 = kstep * 32 + (L >> 4) * 8;
        bf16x8 v;
#pragma unroll
        for (int j = 0; j < 8; j++) v[j] = (__bf16)W2[(k0 + j) * 64 + oc];
        ((bf16x8*)wf2)[g2] = v;
    }
}

// ---------------- gemm1 body: 16 rows/wave, 64 rows/block ----------------
__device__ __forceinline__ void gemm1_body(int bid, int tid, const float* __restrict__ x,
                                           const bf16x8* __restrict__ wfrag,
                                           __bf16* __restrict__ outp, int M) {
    int lane = tid & 63;
    int wave = tid >> 6;
    int col = lane & 15, q = lane >> 4;
    long r0 = (long)bid * 64 + wave * 16 + col;
    long r0c = (r0 < M) ? r0 : (M - 1);

    f32x4 acc[8];
#pragma unroll
    for (int o = 0; o < 8; o++) acc[o] = (f32x4){0.f, 0.f, 0.f, 0.f};

#pragma unroll
    for (int ks = 0; ks < 8; ks++) {
        int k0 = ks * 32 + q * 8;
        const float* A0 = x + r0c * 256 + k0;
        float4 f0a = *(const float4*)A0;
        float4 f0b = *(const float4*)(A0 + 4);
        bf16x8 b0;
        b0[0] = (__bf16)f0a.x; b0[1] = (__bf16)f0a.y; b0[2] = (__bf16)f0a.z; b0[3] = (__bf16)f0a.w;
        b0[4] = (__bf16)f0b.x; b0[5] = (__bf16)f0b.y; b0[6] = (__bf16)f0b.z; b0[7] = (__bf16)f0b.w;
#pragma unroll
        for (int ot = 0; ot < 8; ot++) {
            bf16x8 a = wfrag[(ks * 8 + ot) * 64 + lane];
            acc[ot] = __builtin_amdgcn_mfma_f32_16x16x32_bf16(a, b0, acc[ot], 0, 0, 0);
        }
    }

    if (r0 < M) {
#pragma unroll
        for (int ot = 0; ot < 8; ot++) {
            int oc = ot * 16 + q * 4;
            bf16x4 v;
#pragma unroll
            for (int r = 0; r < 4; r++) v[r] = (__bf16)acc[ot][r];
            *(bf16x4*)(outp + r0 * 128 + oc) = v;
        }
    }
}

// ---------------- K1: P1 bucket scatter (once) | gemm1 (reps x) ----------------
__global__ __launch_bounds__(256) void p1_gemm1_kernel(
    const int* __restrict__ src, const int* __restrict__ dst, int E, int p1Blocks,
    unsigned* __restrict__ gcnt, unsigned* __restrict__ ebuf,
    const float* __restrict__ x, const bf16x8* __restrict__ wf1,
    __bf16* __restrict__ h1u, int M, int reps, long pstride) {
    __shared__ unsigned sPacked[P1_EPB];  // 16 KB
    __shared__ int sCnt[256];
    if ((int)blockIdx.x < p1Blocks) {
        int t = threadIdx.x;
        sCnt[t] = 0;
        __syncthreads();
        long e0 = (long)blockIdx.x * P1_EPB;
        int cnt = (int)(E - e0);
        if (cnt > P1_EPB) cnt = P1_EPB;
        for (int i = t; i < cnt; i += 256) {
            unsigned s = (unsigned)src[e0 + i];
            unsigned d = (unsigned)dst[e0 + i];
            sPacked[i] = (s << 16) | d;          // both < 2^16
            atomicAdd(&sCnt[d >> 8], 1);
        }
        __syncthreads();
        int base = 0;
        if (t < NBKT) base = (int)atomicAdd(&gcnt[t], (unsigned)sCnt[t]);
        __syncthreads();
        if (t < NBKT) sCnt[t] = t * EB_CAP + base;   // global cursor
        __syncthreads();
        for (int i = t; i < cnt; i += 256) {
            unsigned p = sPacked[i];
            int b = (int)((p & 0xffffu) >> 8);
            int pos = atomicAdd(&sCnt[b], 1);
            if (pos < (b + 1) * EB_CAP) ebuf[pos] = p;
        }
    } else {
        for (int r = 0; r < reps; r++)
            gemm1_body(blockIdx.x - p1Blocks, threadIdx.x, x + r * pstride, wf1, h1u, M);
    }
}

// ---------------- K2: per-bucket dense CSR (reps x, idempotent) ----------------
__global__ __launch_bounds__(256) void csr_kernel(
    const unsigned* __restrict__ gcnt, const unsigned* __restrict__ ebuf,
    int* __restrict__ csr, int2* __restrict__ se, float* __restrict__ dinv, int N,
    int reps, long pstride) {
    __shared__ unsigned sEdges[EB_CAP];  // 18 KB
    __shared__ int sCnt[256];
    __shared__ int sScan[256];
    int b = blockIdx.x, t = threadIdx.x;
    for (int r = 0; r < reps; r++) {
        __syncthreads();                     // rep boundary: sEdges/sCnt reuse
        int m = (int)gcnt[b];
        if (m > EB_CAP) m = EB_CAP;
        sCnt[t] = 0;
        __syncthreads();
        const unsigned* eb = ebuf + b * EB_CAP + r * pstride;
        for (int i = t; i < m; i += 256) {
            unsigned p = eb[i];
            sEdges[i] = p;
            atomicAdd(&sCnt[p & 255u], 1);
        }
        __syncthreads();
        int c = sCnt[t];
        int pad = (c + 7) & ~7;                 // pad run to multiple of 8
        sScan[t] = pad;
        __syncthreads();
        for (int off = 1; off < 256; off <<= 1) {
            int v = (t >= off) ? sScan[t - off] : 0;
            __syncthreads();
            sScan[t] += v;
            __syncthreads();
        }
        int start = b * CSR_CAP + sScan[t] - pad;   // exclusive scan; multiple of 8
        int node = (b << 8) + t;
        if (node < N) {
            se[node] = make_int2(start, start + pad);  // loop extent = padded
            dinv[node] = rsqrtf((float)c + 1.0f);      // true degree (+1 self-loop)
        }
        __syncthreads();
        sCnt[t] = start;                         // reuse as cursor
        __syncthreads();
        for (int i = t; i < m; i += 256) {
            unsigned p = sEdges[i];
            int pos = atomicAdd(&sCnt[p & 255u], 1);
            csr[pos] = (int)(p >> 16);           // src
        }
        // sentinel-fill pad slots (dinv[N]=0 -> zero contribution)
        if (node < N) {
            for (int k = start + c; k < start + pad; k++) csr[k] = N;
        }
    }
}

// ---------------- K3: agg128 (R7 core) + fused gemm2, reps x ----------------
#define ACC8()                                             \
    do {                                                   \
        a0x += bflo(v0) * w0; a0y += bfhi(v0) * w0;        \
        a1x += bflo(v1) * w1; a1y += bfhi(v1) * w1;        \
        a2x += bflo(v2) * w2; a2y += bfhi(v2) * w2;        \
        a3x += bflo(v3) * w3; a3y += bfhi(v3) * w3;        \
        a0x += bflo(v4) * w4; a0y += bfhi(v4) * w4;        \
        a1x += bflo(v5) * w5; a1y += bfhi(v5) * w5;        \
        a2x += bflo(v6) * w6; a2y += bfhi(v6) * w6;        \
        a3x += bflo(v7) * w7; a3y += bfhi(v7) * w7;        \
    } while (0)

__global__ __launch_bounds__(256) void agg128_gemm2_kernel(
    const __bf16* __restrict__ h, const int* __restrict__ csr,
    const int2* __restrict__ se, const float* __restrict__ dinv,
    const float* __restrict__ bias, const bf16x8* __restrict__ wf2,
    __bf16* __restrict__ h2s, int N, int reps, long pstride) {
    __shared__ __bf16 stash[16 * 132];    // 16 rows x 132(pad) bf16 = 4.2 KB
    int wave = threadIdx.x >> 6, lane = threadIdx.x & 63;
    int n0 = blockIdx.x * 16;             // block's 16 nodes
    unsigned* stw = (unsigned*)stash;     // dword view, row stride 66 words
    float2 bv = ((const float2*)bias)[lane];

    for (int r = 0; r < reps; r++) {
        const unsigned* hp = (const unsigned*)(h + r * pstride);  // 2 bf16/word, stride 64
#pragma unroll 1
        for (int i = 0; i < 4; i++) {
            int n = n0 + wave * 4 + i;
            float ox = 0.f, oy = 0.f;
            if (n < N) {
                int2 s_e = se[n];
                int start = s_e.x, m = s_e.y - s_e.x;    // m % 8 == 0
                float dn = dinv[n];
                const int* sl = csr + start;             // 32B-aligned
                unsigned self = hp[(long)n * 64 + lane];
                float a0x = bflo(self) * dn, a0y = bfhi(self) * dn;  // *dn at end -> dinv^2
                float a1x = 0.f, a1y = 0.f, a2x = 0.f, a2y = 0.f, a3x = 0.f, a3y = 0.f;
                if (m > 0) {
                    int4 c0 = *(const int4*)sl;
                    int4 c1 = *(const int4*)(sl + 4);
                    int i0 = __builtin_amdgcn_readfirstlane(c0.x);
                    int i1 = __builtin_amdgcn_readfirstlane(c0.y);
                    int i2 = __builtin_amdgcn_readfirstlane(c0.z);
                    int i3 = __builtin_amdgcn_readfirstlane(c0.w);
                    int i4 = __builtin_amdgcn_readfirstlane(c1.x);
                    int i5 = __builtin_amdgcn_readfirstlane(c1.y);
                    int i6 = __builtin_amdgcn_readfirstlane(c1.z);
                    int i7 = __builtin_amdgcn_readfirstlane(c1.w);
                    unsigned v0 = hp[(long)i0 * 64 + lane], v1 = hp[(long)i1 * 64 + lane];
                    unsigned v2 = hp[(long)i2 * 64 + lane], v3 = hp[(long)i3 * 64 + lane];
                    unsigned v4 = hp[(long)i4 * 64 + lane], v5 = hp[(long)i5 * 64 + lane];
                    unsigned v6 = hp[(long)i6 * 64 + lane], v7 = hp[(long)i7 * 64 + lane];
                    float w0 = dinv[i0], w1 = dinv[i1], w2 = dinv[i2], w3 = dinv[i3];
                    float w4 = dinv[i4], w5 = dinv[i5], w6 = dinv[i6], w7 = dinv[i7];
                    int4 d0 = *(const int4*)(sl + 8);   // safe over-read (se follows csr)
                    int4 d1 = *(const int4*)(sl + 12);
                    for (int j = 8; j < m; j += 8) {
                        int t0 = __builtin_amdgcn_readfirstlane(d0.x);
                        int t1 = __builtin_amdgcn_readfirstlane(d0.y);
                        int t2 = __builtin_amdgcn_readfirstlane(d0.z);
                        int t3 = __builtin_amdgcn_readfirstlane(d0.w);
                        int t4 = __builtin_amdgcn_readfirstlane(d1.x);
                        int t5 = __builtin_amdgcn_readfirstlane(d1.y);
                        int t6 = __builtin_amdgcn_readfirstlane(d1.z);
                        int t7 = __builtin_amdgcn_readfirstlane(d1.w);
                        unsigned u0 = hp[(long)t0 * 64 + lane], u1 = hp[(long)t1 * 64 + lane];
                        unsigned u2 = hp[(long)t2 * 64 + lane], u3 = hp[(long)t3 * 64 + lane];
                        unsigned u4 = hp[(long)t4 * 64 + lane], u5 = hp[(long)t5 * 64 + lane];
                        unsigned u6 = hp[(long)t6 * 64 + lane], u7 = hp[(long)t7 * 64 + lane];
                        float q0 = dinv[t0], q1 = dinv[t1], q2 = dinv[t2], q3 = dinv[t3];
                        float q4 = dinv[t4], q5 = dinv[t5], q6 = dinv[t6], q7 = dinv[t7];
                        d0 = *(const int4*)(sl + j + 8);
                        d1 = *(const int4*)(sl + j + 12);
                        ACC8();
                        v0 = u0; v1 = u1; v2 = u2; v3 = u3; v4 = u4; v5 = u5; v6 = u6; v7 = u7;
                        w0 = q0; w1 = q1; w2 = q2; w3 = q3; w4 = q4; w5 = q5; w6 = q6; w7 = q7;
                    }
                    ACC8();
                }
                ox = fmaxf((a0x + a1x + a2x + a3x) * dn + bv.x, 0.f);
                oy = fmaxf((a0y + a1y + a2y + a3y) * dn + bv.y, 0.f);
            }
            bf16x2 st = {(__bf16)ox, (__bf16)oy};  // invalid nodes stash zeros
            stw[(wave * 4 + i) * 66 + lane] = *(unsigned*)&st;  // conflict-free
        }
        __syncthreads();

        // gemm2 from LDS: rows = 16 stashed nodes (B), wave w -> octile w of wf2 (A)
        int col = lane & 15, q = lane >> 4;
        const __bf16* srow = stash + col * 132;
        f32x4 acc = (f32x4){0.f, 0.f, 0.f, 0.f};
#pragma unroll
        for (int ks = 0; ks < 4; ks++) {
            bf16x8 bb = *(const bf16x8*)(srow + ks * 32 + q * 8);
            bf16x8 a = wf2[(ks * 4 + wave) * 64 + lane];
            acc = __builtin_amdgcn_mfma_f32_16x16x32_bf16(a, bb, acc, 0, 0, 0);
        }
        int node = n0 + col;
        if (node < N) {
            float dn2 = dinv[node];
            bf16x4 v;
#pragma unroll
            for (int rr = 0; rr < 4; rr++) v[rr] = (__bf16)(acc[rr] * dn2);
            *(bf16x4*)(h2s + (long)node * 64 + (wave * 16 + q * 4)) = v;
        }
        __syncthreads();                      // rep boundary: stash reuse
    }
}
#undef ACC8

// ---------------- K4: agg64 (R7 core), reps x ----------------
#define ACC8B()                                                                            \
    do {                                                                                   \
        a0 += __uint_as_float((unsigned)v0 << 16); a1 += __uint_as_float((unsigned)v1 << 16); \
        a2 += __uint_as_float((unsigned)v2 << 16); a3 += __uint_as_float((unsigned)v3 << 16); \
        a0 += __uint_as_float((unsigned)v4 << 16); a1 += __uint_as_float((unsigned)v5 << 16); \
        a2 += __uint_as_float((unsigned)v6 << 16); a3 += __uint_as_float((unsigned)v7 << 16); \
    } while (0)

__global__ __launch_bounds__(256) void agg64_kernel(const __bf16* __restrict__ hs,
                                                    const int* __restrict__ csr,
                                                    const int2* __restrict__ se,
                                                    const float* __restrict__ dinv,
                                                    const float* __restrict__ bias,
                                                    float* __restrict__ outp, int N,
                                                    int reps, long pstride) {
    int gid = blockIdx.x * TPB + threadIdx.x;
    int n = gid >> 6, lane = gid & 63;
    if (n >= N) return;
    int2 s_e = se[n];
    int start = s_e.x, m0 = s_e.y - s_e.x;   // m % 8 == 0
    float dn = dinv[n];
    float bvl = bias[lane];
    for (int r = 0; r < reps; r++) {
        const unsigned short* hp = (const unsigned short*)(hs + r * pstride);  // stride 64
        const int* sl = csr + start;
        int m = m0;
        float a0 = __uint_as_float(((unsigned)hp[(long)n * 64 + lane]) << 16);
        float a1 = 0.f, a2 = 0.f, a3 = 0.f;
        if (m > 0) {
            int4 c0 = *(const int4*)sl;
            int4 c1 = *(const int4*)(sl + 4);
            int i0 = __builtin_amdgcn_readfirstlane(c0.x);
            int i1 = __builtin_amdgcn_readfirstlane(c0.y);
            int i2 = __builtin_amdgcn_readfirstlane(c0.z);
            int i3 = __builtin_amdgcn_readfirstlane(c0.w);
            int i4 = __builtin_amdgcn_readfirstlane(c1.x);
            int i5 = __builtin_amdgcn_readfirstlane(c1.y);
            int i6 = __builtin_amdgcn_readfirstlane(c1.z);
            int i7 = __builtin_amdgcn_readfirstlane(c1.w);
            unsigned short v0 = hp[(long)i0 * 64 + lane], v1 = hp[(long)i1 * 64 + lane];
            unsigned short v2 = hp[(long)i2 * 64 + lane], v3 = hp[(long)i3 * 64 + lane];
            unsigned short v4 = hp[(long)i4 * 64 + lane], v5 = hp[(long)i5 * 64 + lane];
            unsigned short v6 = hp[(long)i6 * 64 + lane], v7 = hp[(long)i7 * 64 + lane];
            int4 d0 = *(const int4*)(sl + 8);
            int4 d1 = *(const int4*)(sl + 12);
            for (int j = 8; j < m; j += 8) {
                int t0 = __builtin_amdgcn_readfirstlane(d0.x);
                int t1 = __builtin_amdgcn_readfirstlane(d0.y);
                int t2 = __builtin_amdgcn_readfirstlane(d0.z);
                int t3 = __builtin_amdgcn_readfirstlane(d0.w);
                int t4 = __builtin_amdgcn_readfirstlane(d1.x);
                int t5 = __builtin_amdgcn_readfirstlane(d1.y);
                int t6 = __builtin_amdgcn_readfirstlane(d1.z);
                int t7 = __builtin_amdgcn_readfirstlane(d1.w);
                unsigned short u0 = hp[(long)t0 * 64 + lane], u1 = hp[(long)t1 * 64 + lane];
                unsigned short u2 = hp[(long)t2 * 64 + lane], u3 = hp[(long)t3 * 64 + lane];
                unsigned short u4 = hp[(long)t4 * 64 + lane], u5 = hp[(long)t5 * 64 + lane];
                unsigned short u6 = hp[(long)t6 * 64 + lane], u7 = hp[(long)t7 * 64 + lane];
                d0 = *(const int4*)(sl + j + 8);
                d1 = *(const int4*)(sl + j + 12);
                ACC8B();
                v0 = u0; v1 = u1; v2 = u2; v3 = u3; v4 = u4; v5 = u5; v6 = u6; v7 = u7;
            }
            ACC8B();
        }
        outp[(long)n * 64 + lane] = (a0 + a1 + a2 + a3) * dn + bvl;
    }
}
#undef ACC8B

static inline int cdiv(long a, long b) { return (int)((a + b - 1) / b); }

extern "C" void kernel_launch(void* const* d_in, const int* in_sizes, int n_in,
                              void* d_out, int out_size, void* d_ws, size_t ws_size,
                              hipStream_t stream) {
    const float* x  = (const float*)d_in[0];
    const int*   ei = (const int*)d_in[1];
    const float* W1 = (const float*)d_in[2];
    const float* b1 = (const float*)d_in[3];
    const float* W2 = (const float*)d_in[4];
    const float* b2 = (const float*)d_in[5];

    const int IN_C = 256;
    const int N = in_sizes[0] / IN_C;   // 50000
    const int E = in_sizes[1] / 2;      // 800000
    const int* src = ei;
    const int* dst = ei + E;

    char* w = (char*)d_ws;
    size_t off = 0;
    auto alloc = [&](size_t bytes) { void* p = w + off; off = (off + bytes + 255) & ~255ull; return p; };
    __bf16*   h1u  = (__bf16*)alloc((size_t)(N + 1) * 128 * 2); // +sentinel row
    __bf16*   h2s  = (__bf16*)alloc((size_t)(N + 1) * 64 * 2);  // +sentinel row (zeroed)
    unsigned* ebuf = (unsigned*)alloc((size_t)NBKT * EB_CAP * 4);
    int*      csr  = (int*)alloc((size_t)NBKT * CSR_CAP * 4);
    int2*     se   = (int2*)alloc((size_t)N * 8);
    float*    dinv = (float*)alloc((size_t)(N + 1) * 4);        // +sentinel 0
    unsigned* gcnt = (unsigned*)alloc(NBKT * 4);
    __bf16*   wf1  = (__bf16*)alloc(64 * 64 * 8 * 2);
    __bf16*   wf2  = (__bf16*)alloc(16 * 64 * 8 * 2);

    const long PSTRIDE = 0;   // runtime-opaque 0: defeats cross-rep CSE

    // K0: clear bucket counters + sentinel rows (block 0) + pack W frags
    int wprepBlocks = cdiv(64 * 64 + 16 * 64, TPB);  // 20
    clear_wprep_kernel<<<1 + wprepBlocks, TPB, 0, stream>>>(gcnt, dinv, h2s, N,
                                                            W1, W2, wf1, wf2);

    // K1: bucket scatter (once) | gemm1 (x3 for visibility)
    int p1Blocks = cdiv(E, P1_EPB);                  // 196
    int gemmBlocks = cdiv(N, 64);                    // 782
    p1_gemm1_kernel<<<p1Blocks + gemmBlocks, TPB, 0, stream>>>(
        src, dst, E, p1Blocks, gcnt, ebuf, x, (const bf16x8*)wf1, h1u, N, 3, PSTRIDE);

    // K2: per-bucket dense CSR (x6 for visibility)
    csr_kernel<<<NBKT, TPB, 0, stream>>>(gcnt, ebuf, csr, se, dinv, N, 6, PSTRIDE);

    // K3: layer-1 aggregate + fused gemm2 (x3 for visibility)
    agg128_gemm2_kernel<<<cdiv(N, 16), TPB, 0, stream>>>(h1u, csr, se, dinv, b1,
                                                         (const bf16x8*)wf2, h2s, N,
                                                         3, PSTRIDE);

    // K4: layer-2 aggregate -> d_out (x3 for visibility)
    agg64_kernel<<<cdiv((long)N * 64, TPB), TPB, 0, stream>>>(h2s, csr, se, dinv, b2,
                                                              (float*)d_out, N, 3, PSTRIDE);
}

// Round 11
// 188.942 us; speedup vs baseline: 1.7467x; 1.7467x over previous
//
#include <hip/hip_runtime.h>

// GCN 2-layer (R11): 4 launches (K0 eliminated), informed by R10 diagnostics:
// kernel work ~72us (K3 34, K4 ~14, K1 ~14, K2 ~7), boundaries ~13-17us each.
// - P1: R6's private-slice scatter (98 blocks x 8192 edges, LDS cursors only,
//   no global atomics, no pre-cleared state) [proven R6].
// - gemm1: W1 fragments staged per-OCTILE via 8KB LDS tile (pack outside the
//   MFMA sequence; fixes R6's in-loop scalar-load mistake), 64 rows/block [R7].
// - K2: R6's concat-CSR + sentinels + wf2 frag pack (4 extra blocks).
// - K3 agg128+gemm2, K4 agg64: byte-identical to R7 (best, 179.4us).
// Dead ends (measured): grid-barrier persistent kernels (R2/R5: ~100us/barrier
// cross-XCD), per-wave node batching (R3: 25% occ), in-loop direct-W (R6),
// wide gathers (R9: null — aggs are beyond-L2-BW-bound at ~2.4TB/s, not issue).

#define TPB 256
#define NBKT 196        // ceil(50000/256) buckets of 256 nodes
#define P1_EPB 8192     // edges per P1 block
#define PB_CAP 96       // per-(block,bucket) slots: mean 41.8 + 8.5 sigma
#define EB_CAP 4608     // per-bucket total: mean ~4081 + 8 sigma
#define CSR_CAP 6400    // 4608 + 256*7 pad-to-8 worst case

typedef __bf16 bf16x8 __attribute__((ext_vector_type(8)));
typedef __bf16 bf16x4 __attribute__((ext_vector_type(4)));
typedef __bf16 bf16x2 __attribute__((ext_vector_type(2)));
typedef float f32x4 __attribute__((ext_vector_type(4)));

__device__ __forceinline__ float bflo(unsigned u) { return __uint_as_float(u << 16); }
__device__ __forceinline__ float bfhi(unsigned u) { return __uint_as_float(u & 0xffff0000u); }

// ---------------- K1: P1 private-slice scatter | gemm1 (LDS-staged W1) ----------------
// gemm1: 16 rows/wave, 64 rows/block. Per octile ot: stage the 8-kstep frag
// strip (8KB) into LDS cooperatively (outside the MFMA sequence), sync, then
// 8 MFMA from LDS. A-frag: lane L holds A[m=L&15][k=(L>>4)*8+j],
// A[m][k] = W1[k][ot*16+m].
__global__ __launch_bounds__(256) void p1_gemm1_kernel(
    const int* __restrict__ src, const int* __restrict__ dst, int E, int p1Blocks,
    unsigned* __restrict__ gcnt2, unsigned* __restrict__ ebuf2,
    const float* __restrict__ x, const float* __restrict__ W1,
    __bf16* __restrict__ h1u, int M) {
    __shared__ int sCnt[256];          // P1 cursors (1 KB)
    __shared__ bf16x8 wtile[8 * 64];   // gemm1 frag strip (8 KB)
    int bx = (int)blockIdx.x, t = threadIdx.x;
    if (bx < p1Blocks) {
        sCnt[t] = 0;
        __syncthreads();
        long e0 = (long)bx * P1_EPB;
        int cnt = (int)(E - e0);
        if (cnt > P1_EPB) cnt = P1_EPB;
        unsigned* myslice = ebuf2 + (long)bx * NBKT * PB_CAP;
        for (int i = t; i < cnt; i += 256) {
            unsigned s = (unsigned)src[e0 + i];
            unsigned d = (unsigned)dst[e0 + i];
            int b = (int)(d >> 8);
            int pos = atomicAdd(&sCnt[b], 1);
            if (pos < PB_CAP) myslice[b * PB_CAP + pos] = (s << 16) | d;  // both < 2^16
        }
        __syncthreads();
        if (t < NBKT) {
            int c = sCnt[t];
            gcnt2[bx * NBKT + t] = (unsigned)(c < PB_CAP ? c : PB_CAP);
        }
        return;
    }
    // ---- gemm1 ----
    int bid = bx - p1Blocks;
    int lane = t & 63, wave = t >> 6;
    int col = lane & 15, q = lane >> 4;
    long r0 = (long)bid * 64 + wave * 16 + col;
    long r0c = (r0 < M) ? r0 : (M - 1);

    // B-side: this row's 8 ksteps in registers (32 VGPRs)
    bf16x8 bvec[8];
#pragma unroll
    for (int ks = 0; ks < 8; ks++) {
        int k0 = ks * 32 + q * 8;
        const float* A0 = x + r0c * 256 + k0;
        float4 f0a = *(const float4*)A0;
        float4 f0b = *(const float4*)(A0 + 4);
        bf16x8 b0;
        b0[0] = (__bf16)f0a.x; b0[1] = (__bf16)f0a.y; b0[2] = (__bf16)f0a.z; b0[3] = (__bf16)f0a.w;
        b0[4] = (__bf16)f0b.x; b0[5] = (__bf16)f0b.y; b0[6] = (__bf16)f0b.z; b0[7] = (__bf16)f0b.w;
        bvec[ks] = b0;
    }

    f32x4 acc[8];
#pragma unroll
    for (int o = 0; o < 8; o++) acc[o] = (f32x4){0.f, 0.f, 0.f, 0.f};

#pragma unroll 1
    for (int ot = 0; ot < 8; ot++) {
        // stage frag strip for this octile: 512 slots of 16 B (2 per thread)
#pragma unroll
        for (int s = t; s < 512; s += 256) {
            int ksS = s >> 6, L = s & 63;
            int c = ot * 16 + (L & 15);
            int k0 = ksS * 32 + (L >> 4) * 8;
            bf16x8 v;
#pragma unroll
            for (int j = 0; j < 8; j++) v[j] = (__bf16)W1[(k0 + j) * 128 + c];
            wtile[s] = v;
        }
        __syncthreads();
#pragma unroll
        for (int ks = 0; ks < 8; ks++)
            acc[ot] = __builtin_amdgcn_mfma_f32_16x16x32_bf16(wtile[ks * 64 + lane],
                                                              bvec[ks], acc[ot], 0, 0, 0);
        __syncthreads();   // wtile reused next octile
    }

    if (r0 < M) {
#pragma unroll
        for (int ot = 0; ot < 8; ot++) {
            int oc = ot * 16 + q * 4;
            bf16x4 v;
#pragma unroll
            for (int r = 0; r < 4; r++) v[r] = (__bf16)acc[ot][r];
            *(bf16x4*)(h1u + r0 * 128 + oc) = v;
        }
    }
}

// ---------------- K2: concat chunks -> dense CSR | wf2 pack | sentinels ----------------
__global__ __launch_bounds__(256) void csr_kernel(
    const unsigned* __restrict__ gcnt2, const unsigned* __restrict__ ebuf2,
    int* __restrict__ csr, int2* __restrict__ se, float* __restrict__ dinv,
    __bf16* __restrict__ h2s, int N, int p1Blocks,
    const float* __restrict__ W2, __bf16* __restrict__ wf2) {
    __shared__ unsigned sEdges[EB_CAP];  // 18 KB
    __shared__ int sCnt[256];
    __shared__ int sScan[256];
    __shared__ int sTot;
    int b = blockIdx.x, t = threadIdx.x;
    if (b >= NBKT) {  // wf2 frag pack: 16 frags x 64 lanes = 1024 threads (4 blocks)
        int g2 = (b - NBKT) * 256 + t;
        if (g2 < 16 * 64) {
            int frag = g2 >> 6, L = g2 & 63;
            int kstep = frag >> 2, oct = frag & 3;
            int oc = oct * 16 + (L & 15);
            int k0 = kstep * 32 + (L >> 4) * 8;
            bf16x8 v;
#pragma unroll
            for (int j = 0; j < 8; j++) v[j] = (__bf16)W2[(k0 + j) * 64 + oc];
            ((bf16x8*)wf2)[g2] = v;
        }
        return;
    }
    if (b == 0) {  // sentinels (used only by K3/K4)
        if (t == 0) dinv[N] = 0.0f;
        if (t < 32) ((unsigned*)(h2s + (long)N * 64))[t] = 0u;  // sentinel row = 0
    }
    sCnt[t] = 0;
    if (t == 0) sTot = 0;
    __syncthreads();
    // concat per-block chunks for this bucket into sEdges (+ per-node counts)
    if (t < p1Blocks) {
        int c = (int)gcnt2[t * NBKT + b];
        int pos = atomicAdd(&sTot, c);
        const unsigned* chunk = ebuf2 + ((long)t * NBKT + b) * PB_CAP;
        for (int i = 0; i < c; i++) {
            if (pos + i >= EB_CAP) break;
            unsigned p = chunk[i];
            sEdges[pos + i] = p;
            atomicAdd(&sCnt[p & 255u], 1);
        }
    }
    __syncthreads();
    int m = sTot;
    if (m > EB_CAP) m = EB_CAP;
    int c = sCnt[t];
    int pad = (c + 7) & ~7;                 // pad run to multiple of 8
    sScan[t] = pad;
    __syncthreads();
    for (int off = 1; off < 256; off <<= 1) {
        int v = (t >= off) ? sScan[t - off] : 0;
        __syncthreads();
        sScan[t] += v;
        __syncthreads();
    }
    int start = b * CSR_CAP + sScan[t] - pad;   // exclusive scan; multiple of 8
    int node = (b << 8) + t;
    if (node < N) {
        se[node] = make_int2(start, start + pad);  // loop extent = padded
        dinv[node] = rsqrtf((float)c + 1.0f);      // true degree (+1 self-loop)
    }
    __syncthreads();
    sCnt[t] = start;                         // reuse as cursor
    __syncthreads();
    for (int i = t; i < m; i += 256) {
        unsigned p = sEdges[i];
        int pos = atomicAdd(&sCnt[p & 255u], 1);
        csr[pos] = (int)(p >> 16);           // src
    }
    // sentinel-fill pad slots (dinv[N]=0 -> zero contribution)
    if (node < N) {
        for (int k = start + c; k < start + pad; k++) csr[k] = N;
    }
}

// ---------------- K3: agg128 (pipelined, scalarized) + fused gemm2 [R7] ----------------
#define ACC8()                                             \
    do {                                                   \
        a0x += bflo(v0) * w0; a0y += bfhi(v0) * w0;        \
        a1x += bflo(v1) * w1; a1y += bfhi(v1) * w1;        \
        a2x += bflo(v2) * w2; a2y += bfhi(v2) * w2;        \
        a3x += bflo(v3) * w3; a3y += bfhi(v3) * w3;        \
        a0x += bflo(v4) * w4; a0y += bfhi(v4) * w4;        \
        a1x += bflo(v5) * w5; a1y += bfhi(v5) * w5;        \
        a2x += bflo(v6) * w6; a2y += bfhi(v6) * w6;        \
        a3x += bflo(v7) * w7; a3y += bfhi(v7) * w7;        \
    } while (0)

__global__ __launch_bounds__(256) void agg128_gemm2_kernel(
    const __bf16* __restrict__ h, const int* __restrict__ csr,
    const int2* __restrict__ se, const float* __restrict__ dinv,
    const float* __restrict__ bias, const bf16x8* __restrict__ wf2,
    __bf16* __restrict__ h2s, int N) {
    __shared__ __bf16 stash[16 * 132];    // 16 rows x 132(pad) bf16 = 4.2 KB
    int wave = threadIdx.x >> 6, lane = threadIdx.x & 63;
    int n0 = blockIdx.x * 16;             // block's 16 nodes
    unsigned* stw = (unsigned*)stash;     // dword view, row stride 66 words

    float2 bv = ((const float2*)bias)[lane];
#pragma unroll 1
    for (int i = 0; i < 4; i++) {
        int n = n0 + wave * 4 + i;
        float ox = 0.f, oy = 0.f;
        if (n < N) {
            int2 s_e = se[n];
            int start = s_e.x, m = s_e.y - s_e.x;    // m % 8 == 0
            float dn = dinv[n];
            const unsigned* hp = (const unsigned*)h;  // 2 bf16/word, stride 64 words
            const int* sl = csr + start;              // 32B-aligned
            unsigned self = hp[(long)n * 64 + lane];
            float a0x = bflo(self) * dn, a0y = bfhi(self) * dn;  // *dn at end -> dinv^2
            float a1x = 0.f, a1y = 0.f, a2x = 0.f, a2y = 0.f, a3x = 0.f, a3y = 0.f;
            if (m > 0) {
                int4 c0 = *(const int4*)sl;
                int4 c1 = *(const int4*)(sl + 4);
                int i0 = __builtin_amdgcn_readfirstlane(c0.x);
                int i1 = __builtin_amdgcn_readfirstlane(c0.y);
                int i2 = __builtin_amdgcn_readfirstlane(c0.z);
                int i3 = __builtin_amdgcn_readfirstlane(c0.w);
                int i4 = __builtin_amdgcn_readfirstlane(c1.x);
                int i5 = __builtin_amdgcn_readfirstlane(c1.y);
                int i6 = __builtin_amdgcn_readfirstlane(c1.z);
                int i7 = __builtin_amdgcn_readfirstlane(c1.w);
                unsigned v0 = hp[(long)i0 * 64 + lane], v1 = hp[(long)i1 * 64 + lane];
                unsigned v2 = hp[(long)i2 * 64 + lane], v3 = hp[(long)i3 * 64 + lane];
                unsigned v4 = hp[(long)i4 * 64 + lane], v5 = hp[(long)i5 * 64 + lane];
                unsigned v6 = hp[(long)i6 * 64 + lane], v7 = hp[(long)i7 * 64 + lane];
                float w0 = dinv[i0], w1 = dinv[i1], w2 = dinv[i2], w3 = dinv[i3];
                float w4 = dinv[i4], w5 = dinv[i5], w6 = dinv[i6], w7 = dinv[i7];
                int4 d0 = *(const int4*)(sl + 8);   // safe over-read (se follows csr)
                int4 d1 = *(const int4*)(sl + 12);
                for (int j = 8; j < m; j += 8) {
                    int t0 = __builtin_amdgcn_readfirstlane(d0.x);
                    int t1 = __builtin_amdgcn_readfirstlane(d0.y);
                    int t2 = __builtin_amdgcn_readfirstlane(d0.z);
                    int t3 = __builtin_amdgcn_readfirstlane(d0.w);
                    int t4 = __builtin_amdgcn_readfirstlane(d1.x);
                    int t5 = __builtin_amdgcn_readfirstlane(d1.y);
                    int t6 = __builtin_amdgcn_readfirstlane(d1.z);
                    int t7 = __builtin_amdgcn_readfirstlane(d1.w);
                    unsigned u0 = hp[(long)t0 * 64 + lane], u1 = hp[(long)t1 * 64 + lane];
                    unsigned u2 = hp[(long)t2 * 64 + lane], u3 = hp[(long)t3 * 64 + lane];
                    unsigned u4 = hp[(long)t4 * 64 + lane], u5 = hp[(long)t5 * 64 + lane];
                    unsigned u6 = hp[(long)t6 * 64 + lane], u7 = hp[(long)t7 * 64 + lane];
                    float q0 = dinv[t0], q1 = dinv[t1], q2 = dinv[t2], q3 = dinv[t3];
                    float q4 = dinv[t4], q5 = dinv[t5], q6 = dinv[t6], q7 = dinv[t7];
                    d0 = *(const int4*)(sl + j + 8);
                    d1 = *(const int4*)(sl + j + 12);
                    ACC8();
                    v0 = u0; v1 = u1; v2 = u2; v3 = u3; v4 = u4; v5 = u5; v6 = u6; v7 = u7;
                    w0 = q0; w1 = q1; w2 = q2; w3 = q3; w4 = q4; w5 = q5; w6 = q6; w7 = q7;
                }
                ACC8();
            }
            ox = fmaxf((a0x + a1x + a2x + a3x) * dn + bv.x, 0.f);
            oy = fmaxf((a0y + a1y + a2y + a3y) * dn + bv.y, 0.f);
        }
        bf16x2 st = {(__bf16)ox, (__bf16)oy};  // invalid nodes stash zeros
        stw[(wave * 4 + i) * 66 + lane] = *(unsigned*)&st;  // conflict-free (measured 0)
    }
    __syncthreads();

    // gemm2 from LDS: rows = 16 stashed nodes (B), wave w -> octile w of wf2 (A)
    int col = lane & 15, q = lane >> 4;
    const __bf16* srow = stash + col * 132;
    f32x4 acc = (f32x4){0.f, 0.f, 0.f, 0.f};
#pragma unroll
    for (int ks = 0; ks < 4; ks++) {
        bf16x8 bb = *(const bf16x8*)(srow + ks * 32 + q * 8);
        bf16x8 a = wf2[(ks * 4 + wave) * 64 + lane];
        acc = __builtin_amdgcn_mfma_f32_16x16x32_bf16(a, bb, acc, 0, 0, 0);
    }
    int node = n0 + col;
    if (node < N) {
        float dn2 = dinv[node];
        bf16x4 v;
#pragma unroll
        for (int r = 0; r < 4; r++) v[r] = (__bf16)(acc[r] * dn2);
        *(bf16x4*)(h2s + (long)node * 64 + (wave * 16 + q * 4)) = v;
    }
}
#undef ACC8

// ---------------- K4: agg64 (h2s pre-scaled by dinv[row]; sentinel row = 0) [R7] ----------------
#define ACC8B()                                                                            \
    do {                                                                                   \
        a0 += __uint_as_float((unsigned)v0 << 16); a1 += __uint_as_float((unsigned)v1 << 16); \
        a2 += __uint_as_float((unsigned)v2 << 16); a3 += __uint_as_float((unsigned)v3 << 16); \
        a0 += __uint_as_float((unsigned)v4 << 16); a1 += __uint_as_float((unsigned)v5 << 16); \
        a2 += __uint_as_float((unsigned)v6 << 16); a3 += __uint_as_float((unsigned)v7 << 16); \
    } while (0)

__global__ __launch_bounds__(256) void agg64_kernel(const __bf16* __restrict__ hs,
                                                    const int* __restrict__ csr,
                                                    const int2* __restrict__ se,
                                                    const float* __restrict__ dinv,
                                                    const float* __restrict__ bias,
                                                    float* __restrict__ outp, int N) {
    int gid = blockIdx.x * TPB + threadIdx.x;
    int n = gid >> 6, lane = gid & 63;
    if (n >= N) return;
    int2 s_e = se[n];
    int start = s_e.x, m = s_e.y - s_e.x;    // m % 8 == 0
    float dn = dinv[n];
    const unsigned short* hp = (const unsigned short*)hs;  // row stride 64
    const int* sl = csr + start;
    float a0 = __uint_as_float(((unsigned)hp[(long)n * 64 + lane]) << 16);
    float a1 = 0.f, a2 = 0.f, a3 = 0.f;
    if (m > 0) {
        int4 c0 = *(const int4*)sl;
        int4 c1 = *(const int4*)(sl + 4);
        int i0 = __builtin_amdgcn_readfirstlane(c0.x);
        int i1 = __builtin_amdgcn_readfirstlane(c0.y);
        int i2 = __builtin_amdgcn_readfirstlane(c0.z);
        int i3 = __builtin_amdgcn_readfirstlane(c0.w);
        int i4 = __builtin_amdgcn_readfirstlane(c1.x);
        int i5 = __builtin_amdgcn_readfirstlane(c1.y);
        int i6 = __builtin_amdgcn_readfirstlane(c1.z);
        int i7 = __builtin_amdgcn_readfirstlane(c1.w);
        unsigned short v0 = hp[(long)i0 * 64 + lane], v1 = hp[(long)i1 * 64 + lane];
        unsigned short v2 = hp[(long)i2 * 64 + lane], v3 = hp[(long)i3 * 64 + lane];
        unsigned short v4 = hp[(long)i4 * 64 + lane], v5 = hp[(long)i5 * 64 + lane];
        unsigned short v6 = hp[(long)i6 * 64 + lane], v7 = hp[(long)i7 * 64 + lane];
        int4 d0 = *(const int4*)(sl + 8);
        int4 d1 = *(const int4*)(sl + 12);
        for (int j = 8; j < m; j += 8) {
            int t0 = __builtin_amdgcn_readfirstlane(d0.x);
            int t1 = __builtin_amdgcn_readfirstlane(d0.y);
            int t2 = __builtin_amdgcn_readfirstlane(d0.z);
            int t3 = __builtin_amdgcn_readfirstlane(d0.w);
            int t4 = __builtin_amdgcn_readfirstlane(d1.x);
            int t5 = __builtin_amdgcn_readfirstlane(d1.y);
            int t6 = __builtin_amdgcn_readfirstlane(d1.z);
            int t7 = __builtin_amdgcn_readfirstlane(d1.w);
            unsigned short u0 = hp[(long)t0 * 64 + lane], u1 = hp[(long)t1 * 64 + lane];
            unsigned short u2 = hp[(long)t2 * 64 + lane], u3 = hp[(long)t3 * 64 + lane];
            unsigned short u4 = hp[(long)t4 * 64 + lane], u5 = hp[(long)t5 * 64 + lane];
            unsigned short u6 = hp[(long)t6 * 64 + lane], u7 = hp[(long)t7 * 64 + lane];
            d0 = *(const int4*)(sl + j + 8);
            d1 = *(const int4*)(sl + j + 12);
            ACC8B();
            v0 = u0; v1 = u1; v2 = u2; v3 = u3; v4 = u4; v5 = u5; v6 = u6; v7 = u7;
        }
        ACC8B();
    }
    outp[(long)n * 64 + lane] = (a0 + a1 + a2 + a3) * dn + bias[lane];
}
#undef ACC8B

static inline int cdiv(long a, long b) { return (int)((a + b - 1) / b); }

extern "C" void kernel_launch(void* const* d_in, const int* in_sizes, int n_in,
                              void* d_out, int out_size, void* d_ws, size_t ws_size,
                              hipStream_t stream) {
    const float* x  = (const float*)d_in[0];
    const int*   ei = (const int*)d_in[1];
    const float* W1 = (const float*)d_in[2];
    const float* b1 = (const float*)d_in[3];
    const float* W2 = (const float*)d_in[4];
    const float* b2 = (const float*)d_in[5];

    const int IN_C = 256;
    const int N = in_sizes[0] / IN_C;   // 50000
    const int E = in_sizes[1] / 2;      // 800000
    const int* src = ei;
    const int* dst = ei + E;

    char* w = (char*)d_ws;
    size_t off = 0;
    auto alloc = [&](size_t bytes) { void* p = w + off; off = (off + bytes + 255) & ~255ull; return p; };
    int p1Blocks = cdiv(E, P1_EPB);                              // 98
    __bf16*   h1u   = (__bf16*)alloc((size_t)(N + 1) * 128 * 2); // +sentinel row
    __bf16*   h2s   = (__bf16*)alloc((size_t)(N + 1) * 64 * 2);  // +sentinel row (zeroed by K2)
    unsigned* ebuf2 = (unsigned*)alloc((size_t)p1Blocks * NBKT * PB_CAP * 4);  // 7.4 MB
    int*      csr   = (int*)alloc((size_t)NBKT * CSR_CAP * 4);
    int2*     se    = (int2*)alloc((size_t)N * 8);
    float*    dinv  = (float*)alloc((size_t)(N + 1) * 4);        // +sentinel 0
    unsigned* gcnt2 = (unsigned*)alloc((size_t)p1Blocks * NBKT * 4);
    __bf16*   wf2   = (__bf16*)alloc(16 * 64 * 8 * 2);

    // K1: private-slice bucket scatter | gemm1 (W1 staged per-octile via LDS)
    int gemmBlocks = cdiv(N, 64);                    // 782
    p1_gemm1_kernel<<<p1Blocks + gemmBlocks, TPB, 0, stream>>>(
        src, dst, E, p1Blocks, gcnt2, ebuf2, x, W1, h1u, N);

    // K2: concat chunks -> per-bucket dense CSR + dinv + sentinels | wf2 pack
    csr_kernel<<<NBKT + 4, TPB, 0, stream>>>(gcnt2, ebuf2, csr, se, dinv, h2s, N,
                                             p1Blocks, W2, wf2);

    // K3: layer-1 aggregate (+bias, relu) fused with gemm2 -> h2s
    agg128_gemm2_kernel<<<cdiv(N, 16), TPB, 0, stream>>>(h1u, csr, se, dinv, b1,
                                                         (const bf16x8*)wf2, h2s, N);

    // K4: layer-2 aggregate -> d_out (fp32)
    agg64_kernel<<<cdiv((long)N * 64, TPB), TPB, 0, stream>>>(h2s, csr, se, dinv, b2,
                                                              (float*)d_out, N);
}

// Round 12
// 182.716 us; speedup vs baseline: 1.8062x; 1.0341x over previous
//
#include <hip/hip_runtime.h>

// GCN 2-layer (R12): 4 launches by re-slotting proven bodies along the true
// dependency chain (P1 -> CSR -> agg1 -> agg2; gemm1/packs hide off-path).
// K1: [P1 two-pass scatter w/ block-CONTIGUOUS output (no global atomics, no
//      pre-cleared state) || wf1+wf2 pack (K0 verbatim) || sentinels]
// K2: [CSR concat(196 contiguous chunks)+build || gemm1 (R7 packed-wf1 body)]
// K3: agg128+gemm2, K4: agg64 — byte-identical to R7 (best: 179.4us).
// Budget (R10 diag): fill 41 + kernels ~72 + boundaries ~13-15/launch.
// Dead ends (measured): grid barriers (R2/R5), 16-node waves (R3), in-loop
// direct-W (R6), private-slice P1 (R6/R11: 44-52us), LDS-staged W1 (R11),
// wide gathers (R9 null: aggs beyond-L2-BW-bound ~2.4TB/s).

#define TPB 256
#define NBKT 196        // ceil(50000/256) buckets of 256 nodes
#define P1_BLKS 196     // E/4096 rounded up
#define P1_EPB 4096     // edges per P1 block (16 KB sPacked)
#define EB_CAP 4608     // per-bucket total: mean ~4081 + 8 sigma
#define CSR_CAP 6400    // 4608 + 256*7 pad-to-8 worst case

typedef __bf16 bf16x8 __attribute__((ext_vector_type(8)));
typedef __bf16 bf16x4 __attribute__((ext_vector_type(4)));
typedef __bf16 bf16x2 __attribute__((ext_vector_type(2)));
typedef float f32x4 __attribute__((ext_vector_type(4)));

__device__ __forceinline__ float bflo(unsigned u) { return __uint_as_float(u << 16); }
__device__ __forceinline__ float bfhi(unsigned u) { return __uint_as_float(u & 0xffff0000u); }

// ---------------- K1: P1 contiguous two-pass scatter | W frag pack | sentinels ----------------
// P1 block bx: pass1 edges->sPacked + bucket counts; block-scan -> local bucket
// offsets; pass2 scatter into PRIVATE contiguous ebuf[bx*4096 .. +cnt) (16 KB).
// Emits gcnt2[bx][b], boffs2[bx][b]. No global atomics, no pre-cleared state.
// Pack blocks (196..215): K0's wf1/wf2 fragment pack verbatim. Block 216: sentinels.
__global__ __launch_bounds__(256) void p1_pack_kernel(
    const int* __restrict__ src, const int* __restrict__ dst, int E,
    unsigned* __restrict__ gcnt2, unsigned* __restrict__ boffs2,
    unsigned* __restrict__ ebuf,
    const float* __restrict__ W1, const float* __restrict__ W2,
    __bf16* __restrict__ wf1, __bf16* __restrict__ wf2,
    float* __restrict__ dinv, __bf16* __restrict__ h2s, int N) {
    __shared__ unsigned sPacked[P1_EPB];  // 16 KB
    __shared__ int sCnt[256];
    __shared__ int sScan[256];
    int bx = (int)blockIdx.x, t = threadIdx.x;
    if (bx < P1_BLKS) {
        sCnt[t] = 0;
        __syncthreads();
        long e0 = (long)bx * P1_EPB;
        int cnt = (int)(E - e0);
        if (cnt > P1_EPB) cnt = P1_EPB;
        if (cnt < 0) cnt = 0;
        for (int i = t; i < cnt; i += 256) {
            unsigned s = (unsigned)src[e0 + i];
            unsigned d = (unsigned)dst[e0 + i];
            sPacked[i] = (s << 16) | d;          // both < 2^16
            atomicAdd(&sCnt[d >> 8], 1);
        }
        __syncthreads();
        int c = sCnt[t];                          // t = bucket id (t>=NBKT -> 0)
        sScan[t] = c;
        __syncthreads();
        for (int off = 1; off < 256; off <<= 1) {
            int v = (t >= off) ? sScan[t - off] : 0;
            __syncthreads();
            sScan[t] += v;
            __syncthreads();
        }
        int boff = sScan[t] - c;                  // exclusive scan: local offset
        if (t < NBKT) {
            gcnt2[bx * NBKT + t] = (unsigned)c;
            boffs2[bx * NBKT + t] = (unsigned)boff;
        }
        __syncthreads();
        sCnt[t] = boff;                           // local cursor
        __syncthreads();
        unsigned* myout = ebuf + (long)bx * P1_EPB;   // private 16 KB range
        for (int i = t; i < cnt; i += 256) {
            unsigned p = sPacked[i];
            int b = (int)((p & 0xffffu) >> 8);
            int pos = atomicAdd(&sCnt[b], 1);
            myout[pos] = p;
        }
        return;
    }
    if (bx < P1_BLKS + 20) {  // W frag pack (K0 verbatim addressing)
        int g = (bx - P1_BLKS) * TPB + t;
        if (g < 64 * 64) {  // W1: K=256 (8 ksteps), OC=128 (8 octiles)
            int frag = g >> 6, L = g & 63;
            int kstep = frag >> 3, oct = frag & 7;
            int oc = oct * 16 + (L & 15);
            int k0 = kstep * 32 + (L >> 4) * 8;
            bf16x8 v;
#pragma unroll
            for (int j = 0; j < 8; j++) v[j] = (__bf16)W1[(k0 + j) * 128 + oc];
            ((bf16x8*)wf1)[g] = v;
        } else if (g < 64 * 64 + 16 * 64) {  // W2: K=128 (4), OC=64 (4)
            int g2 = g - 64 * 64;
            int frag = g2 >> 6, L = g2 & 63;
            int kstep = frag >> 2, oct = frag & 3;
            int oc = oct * 16 + (L & 15);
            int k0 = kstep * 32 + (L >> 4) * 8;
            bf16x8 v;
#pragma unroll
            for (int j = 0; j < 8; j++) v[j] = (__bf16)W2[(k0 + j) * 64 + oc];
            ((bf16x8*)wf2)[g2] = v;
        }
        return;
    }
    // sentinel block
    if (t == 0) dinv[N] = 0.0f;
    if (t < 32) ((unsigned*)(h2s + (long)N * 64))[t] = 0u;  // sentinel row = 0
}

// ---------------- gemm1 body: 16 rows/wave, 64 rows/block (R7 verbatim) ----------------
__device__ __forceinline__ void gemm1_body(int bid, int tid, const float* __restrict__ x,
                                           const bf16x8* __restrict__ wfrag,
                                           __bf16* __restrict__ outp, int M) {
    int lane = tid & 63;
    int wave = tid >> 6;
    int col = lane & 15, q = lane >> 4;
    long r0 = (long)bid * 64 + wave * 16 + col;
    long r0c = (r0 < M) ? r0 : (M - 1);

    f32x4 acc[8];
#pragma unroll
    for (int o = 0; o < 8; o++) acc[o] = (f32x4){0.f, 0.f, 0.f, 0.f};

#pragma unroll
    for (int ks = 0; ks < 8; ks++) {
        int k0 = ks * 32 + q * 8;
        const float* A0 = x + r0c * 256 + k0;
        float4 f0a = *(const float4*)A0;
        float4 f0b = *(const float4*)(A0 + 4);
        bf16x8 b0;
        b0[0] = (__bf16)f0a.x; b0[1] = (__bf16)f0a.y; b0[2] = (__bf16)f0a.z; b0[3] = (__bf16)f0a.w;
        b0[4] = (__bf16)f0b.x; b0[5] = (__bf16)f0b.y; b0[6] = (__bf16)f0b.z; b0[7] = (__bf16)f0b.w;
#pragma unroll
        for (int ot = 0; ot < 8; ot++) {
            bf16x8 a = wfrag[(ks * 8 + ot) * 64 + lane];
            acc[ot] = __builtin_amdgcn_mfma_f32_16x16x32_bf16(a, b0, acc[ot], 0, 0, 0);
        }
    }

    if (r0 < M) {
#pragma unroll
        for (int ot = 0; ot < 8; ot++) {
            int oc = ot * 16 + q * 4;
            bf16x4 v;
#pragma unroll
            for (int r = 0; r < 4; r++) v[r] = (__bf16)acc[ot][r];
            *(bf16x4*)(outp + r0 * 128 + oc) = v;
        }
    }
}

// ---------------- K2: CSR concat+build (196 blocks) | gemm1 (782 blocks) ----------------
__global__ __launch_bounds__(256) void csr_gemm1_kernel(
    const unsigned* __restrict__ gcnt2, const unsigned* __restrict__ boffs2,
    const unsigned* __restrict__ ebuf,
    int* __restrict__ csr, int2* __restrict__ se, float* __restrict__ dinv, int N,
    const float* __restrict__ x, const bf16x8* __restrict__ wf1,
    __bf16* __restrict__ h1u) {
    __shared__ unsigned sEdges[EB_CAP];  // 18 KB
    __shared__ int sCnt[256];
    __shared__ int sScan[256];
    __shared__ int sTot;
    int b = (int)blockIdx.x, t = threadIdx.x;
    if (b >= NBKT) {
        gemm1_body(b - NBKT, t, x, wf1, h1u, N);
        return;
    }
    sCnt[t] = 0;
    if (t == 0) sTot = 0;
    __syncthreads();
    // concat the 196 contiguous per-block chunks for this bucket
    if (t < P1_BLKS) {
        int c = (int)gcnt2[t * NBKT + b];
        int off = (int)boffs2[t * NBKT + b];
        int pos = atomicAdd(&sTot, c);
        const unsigned* chunk = ebuf + (long)t * P1_EPB + off;
        for (int i = 0; i < c; i++) {
            if (pos + i >= EB_CAP) break;
            unsigned p = chunk[i];
            sEdges[pos + i] = p;
            atomicAdd(&sCnt[p & 255u], 1);
        }
    }
    __syncthreads();
    int m = sTot;
    if (m > EB_CAP) m = EB_CAP;
    int c = sCnt[t];
    int pad = (c + 7) & ~7;                 // pad run to multiple of 8
    sScan[t] = pad;
    __syncthreads();
    for (int off = 1; off < 256; off <<= 1) {
        int v = (t >= off) ? sScan[t - off] : 0;
        __syncthreads();
        sScan[t] += v;
        __syncthreads();
    }
    int start = b * CSR_CAP + sScan[t] - pad;   // exclusive scan; multiple of 8
    int node = (b << 8) + t;
    if (node < N) {
        se[node] = make_int2(start, start + pad);  // loop extent = padded
        dinv[node] = rsqrtf((float)c + 1.0f);      // true degree (+1 self-loop)
    }
    __syncthreads();
    sCnt[t] = start;                         // reuse as cursor
    __syncthreads();
    for (int i = t; i < m; i += 256) {
        unsigned p = sEdges[i];
        int pos = atomicAdd(&sCnt[p & 255u], 1);
        csr[pos] = (int)(p >> 16);           // src
    }
    // sentinel-fill pad slots (dinv[N]=0 -> zero contribution)
    if (node < N) {
        for (int k = start + c; k < start + pad; k++) csr[k] = N;
    }
}

// ---------------- K3: agg128 (pipelined, scalarized) + fused gemm2 [R7] ----------------
#define ACC8()                                             \
    do {                                                   \
        a0x += bflo(v0) * w0; a0y += bfhi(v0) * w0;        \
        a1x += bflo(v1) * w1; a1y += bfhi(v1) * w1;        \
        a2x += bflo(v2) * w2; a2y += bfhi(v2) * w2;        \
        a3x += bflo(v3) * w3; a3y += bfhi(v3) * w3;        \
        a0x += bflo(v4) * w4; a0y += bfhi(v4) * w4;        \
        a1x += bflo(v5) * w5; a1y += bfhi(v5) * w5;        \
        a2x += bflo(v6) * w6; a2y += bfhi(v6) * w6;        \
        a3x += bflo(v7) * w7; a3y += bfhi(v7) * w7;        \
    } while (0)

__global__ __launch_bounds__(256) void agg128_gemm2_kernel(
    const __bf16* __restrict__ h, const int* __restrict__ csr,
    const int2* __restrict__ se, const float* __restrict__ dinv,
    const float* __restrict__ bias, const bf16x8* __restrict__ wf2,
    __bf16* __restrict__ h2s, int N) {
    __shared__ __bf16 stash[16 * 132];    // 16 rows x 132(pad) bf16 = 4.2 KB
    int wave = threadIdx.x >> 6, lane = threadIdx.x & 63;
    int n0 = blockIdx.x * 16;             // block's 16 nodes
    unsigned* stw = (unsigned*)stash;     // dword view, row stride 66 words

    float2 bv = ((const float2*)bias)[lane];
#pragma unroll 1
    for (int i = 0; i < 4; i++) {
        int n = n0 + wave * 4 + i;
        float ox = 0.f, oy = 0.f;
        if (n < N) {
            int2 s_e = se[n];
            int start = s_e.x, m = s_e.y - s_e.x;    // m % 8 == 0
            float dn = dinv[n];
            const unsigned* hp = (const unsigned*)h;  // 2 bf16/word, stride 64 words
            const int* sl = csr + start;              // 32B-aligned
            unsigned self = hp[(long)n * 64 + lane];
            float a0x = bflo(self) * dn, a0y = bfhi(self) * dn;  // *dn at end -> dinv^2
            float a1x = 0.f, a1y = 0.f, a2x = 0.f, a2y = 0.f, a3x = 0.f, a3y = 0.f;
            if (m > 0) {
                int4 c0 = *(const int4*)sl;
                int4 c1 = *(const int4*)(sl + 4);
                int i0 = __builtin_amdgcn_readfirstlane(c0.x);
                int i1 = __builtin_amdgcn_readfirstlane(c0.y);
                int i2 = __builtin_amdgcn_readfirstlane(c0.z);
                int i3 = __builtin_amdgcn_readfirstlane(c0.w);
                int i4 = __builtin_amdgcn_readfirstlane(c1.x);
                int i5 = __builtin_amdgcn_readfirstlane(c1.y);
                int i6 = __builtin_amdgcn_readfirstlane(c1.z);
                int i7 = __builtin_amdgcn_readfirstlane(c1.w);
                unsigned v0 = hp[(long)i0 * 64 + lane], v1 = hp[(long)i1 * 64 + lane];
                unsigned v2 = hp[(long)i2 * 64 + lane], v3 = hp[(long)i3 * 64 + lane];
                unsigned v4 = hp[(long)i4 * 64 + lane], v5 = hp[(long)i5 * 64 + lane];
                unsigned v6 = hp[(long)i6 * 64 + lane], v7 = hp[(long)i7 * 64 + lane];
                float w0 = dinv[i0], w1 = dinv[i1], w2 = dinv[i2], w3 = dinv[i3];
                float w4 = dinv[i4], w5 = dinv[i5], w6 = dinv[i6], w7 = dinv[i7];
                int4 d0 = *(const int4*)(sl + 8);   // safe over-read (se follows csr)
                int4 d1 = *(const int4*)(sl + 12);
                for (int j = 8; j < m; j += 8) {
                    int t0 = __builtin_amdgcn_readfirstlane(d0.x);
                    int t1 = __builtin_amdgcn_readfirstlane(d0.y);
                    int t2 = __builtin_amdgcn_readfirstlane(d0.z);
                    int t3 = __builtin_amdgcn_readfirstlane(d0.w);
                    int t4 = __builtin_amdgcn_readfirstlane(d1.x);
                    int t5 = __builtin_amdgcn_readfirstlane(d1.y);
                    int t6 = __builtin_amdgcn_readfirstlane(d1.z);
                    int t7 = __builtin_amdgcn_readfirstlane(d1.w);
                    unsigned u0 = hp[(long)t0 * 64 + lane], u1 = hp[(long)t1 * 64 + lane];
                    unsigned u2 = hp[(long)t2 * 64 + lane], u3 = hp[(long)t3 * 64 + lane];
                    unsigned u4 = hp[(long)t4 * 64 + lane], u5 = hp[(long)t5 * 64 + lane];
                    unsigned u6 = hp[(long)t6 * 64 + lane], u7 = hp[(long)t7 * 64 + lane];
                    float q0 = dinv[t0], q1 = dinv[t1], q2 = dinv[t2], q3 = dinv[t3];
                    float q4 = dinv[t4], q5 = dinv[t5], q6 = dinv[t6], q7 = dinv[t7];
                    d0 = *(const int4*)(sl + j + 8);
                    d1 = *(const int4*)(sl + j + 12);
                    ACC8();
                    v0 = u0; v1 = u1; v2 = u2; v3 = u3; v4 = u4; v5 = u5; v6 = u6; v7 = u7;
                    w0 = q0; w1 = q1; w2 = q2; w3 = q3; w4 = q4; w5 = q5; w6 = q6; w7 = q7;
                }
                ACC8();
            }
            ox = fmaxf((a0x + a1x + a2x + a3x) * dn + bv.x, 0.f);
            oy = fmaxf((a0y + a1y + a2y + a3y) * dn + bv.y, 0.f);
        }
        bf16x2 st = {(__bf16)ox, (__bf16)oy};  // invalid nodes stash zeros
        stw[(wave * 4 + i) * 66 + lane] = *(unsigned*)&st;  // conflict-free (measured 0)
    }
    __syncthreads();

    // gemm2 from LDS: rows = 16 stashed nodes (B), wave w -> octile w of wf2 (A)
    int col = lane & 15, q = lane >> 4;
    const __bf16* srow = stash + col * 132;
    f32x4 acc = (f32x4){0.f, 0.f, 0.f, 0.f};
#pragma unroll
    for (int ks = 0; ks < 4; ks++) {
        bf16x8 bb = *(const bf16x8*)(srow + ks * 32 + q * 8);
        bf16x8 a = wf2[(ks * 4 + wave) * 64 + lane];
        acc = __builtin_amdgcn_mfma_f32_16x16x32_bf16(a, bb, acc, 0, 0, 0);
    }
    int node = n0 + col;
    if (node < N) {
        float dn2 = dinv[node];
        bf16x4 v;
#pragma unroll
        for (int r = 0; r < 4; r++) v[r] = (__bf16)(acc[r] * dn2);
        *(bf16x4*)(h2s + (long)node * 64 + (wave * 16 + q * 4)) = v;
    }
}
#undef ACC8

// ---------------- K4: agg64 (h2s pre-scaled by dinv[row]; sentinel row = 0) [R7] ----------------
#define ACC8B()                                                                            \
    do {                                                                                   \
        a0 += __uint_as_float((unsigned)v0 << 16); a1 += __uint_as_float((unsigned)v1 << 16); \
        a2 += __uint_as_float((unsigned)v2 << 16); a3 += __uint_as_float((unsigned)v3 << 16); \
        a0 += __uint_as_float((unsigned)v4 << 16); a1 += __uint_as_float((unsigned)v5 << 16); \
        a2 += __uint_as_float((unsigned)v6 << 16); a3 += __uint_as_float((unsigned)v7 << 16); \
    } while (0)

__global__ __launch_bounds__(256) void agg64_kernel(const __bf16* __restrict__ hs,
                                                    const int* __restrict__ csr,
                                                    const int2* __restrict__ se,
                                                    const float* __restrict__ dinv,
                                                    const float* __restrict__ bias,
                                                    float* __restrict__ outp, int N) {
    int gid = blockIdx.x * TPB + threadIdx.x;
    int n = gid >> 6, lane = gid & 63;
    if (n >= N) return;
    int2 s_e = se[n];
    int start = s_e.x, m = s_e.y - s_e.x;    // m % 8 == 0
    float dn = dinv[n];
    const unsigned short* hp = (const unsigned short*)hs;  // row stride 64
    const int* sl = csr + start;
    float a0 = __uint_as_float(((unsigned)hp[(long)n * 64 + lane]) << 16);
    float a1 = 0.f, a2 = 0.f, a3 = 0.f;
    if (m > 0) {
        int4 c0 = *(const int4*)sl;
        int4 c1 = *(const int4*)(sl + 4);
        int i0 = __builtin_amdgcn_readfirstlane(c0.x);
        int i1 = __builtin_amdgcn_readfirstlane(c0.y);
        int i2 = __builtin_amdgcn_readfirstlane(c0.z);
        int i3 = __builtin_amdgcn_readfirstlane(c0.w);
        int i4 = __builtin_amdgcn_readfirstlane(c1.x);
        int i5 = __builtin_amdgcn_readfirstlane(c1.y);
        int i6 = __builtin_amdgcn_readfirstlane(c1.z);
        int i7 = __builtin_amdgcn_readfirstlane(c1.w);
        unsigned short v0 = hp[(long)i0 * 64 + lane], v1 = hp[(long)i1 * 64 + lane];
        unsigned short v2 = hp[(long)i2 * 64 + lane], v3 = hp[(long)i3 * 64 + lane];
        unsigned short v4 = hp[(long)i4 * 64 + lane], v5 = hp[(long)i5 * 64 + lane];
        unsigned short v6 = hp[(long)i6 * 64 + lane], v7 = hp[(long)i7 * 64 + lane];
        int4 d0 = *(const int4*)(sl + 8);
        int4 d1 = *(const int4*)(sl + 12);
        for (int j = 8; j < m; j += 8) {
            int t0 = __builtin_amdgcn_readfirstlane(d0.x);
            int t1 = __builtin_amdgcn_readfirstlane(d0.y);
            int t2 = __builtin_amdgcn_readfirstlane(d0.z);
            int t3 = __builtin_amdgcn_readfirstlane(d0.w);
            int t4 = __builtin_amdgcn_readfirstlane(d1.x);
            int t5 = __builtin_amdgcn_readfirstlane(d1.y);
            int t6 = __builtin_amdgcn_readfirstlane(d1.z);
            int t7 = __builtin_amdgcn_readfirstlane(d1.w);
            unsigned short u0 = hp[(long)t0 * 64 + lane], u1 = hp[(long)t1 * 64 + lane];
            unsigned short u2 = hp[(long)t2 * 64 + lane], u3 = hp[(long)t3 * 64 + lane];
            unsigned short u4 = hp[(long)t4 * 64 + lane], u5 = hp[(long)t5 * 64 + lane];
            unsigned short u6 = hp[(long)t6 * 64 + lane], u7 = hp[(long)t7 * 64 + lane];
            d0 = *(const int4*)(sl + j + 8);
            d1 = *(const int4*)(sl + j + 12);
            ACC8B();
            v0 = u0; v1 = u1; v2 = u2; v3 = u3; v4 = u4; v5 = u5; v6 = u6; v7 = u7;
        }
        ACC8B();
    }
    outp[(long)n * 64 + lane] = (a0 + a1 + a2 + a3) * dn + bias[lane];
}
#undef ACC8B

static inline int cdiv(long a, long b) { return (int)((a + b - 1) / b); }

extern "C" void kernel_launch(void* const* d_in, const int* in_sizes, int n_in,
                              void* d_out, int out_size, void* d_ws, size_t ws_size,
                              hipStream_t stream) {
    const float* x  = (const float*)d_in[0];
    const int*   ei = (const int*)d_in[1];
    const float* W1 = (const float*)d_in[2];
    const float* b1 = (const float*)d_in[3];
    const float* W2 = (const float*)d_in[4];
    const float* b2 = (const float*)d_in[5];

    const int IN_C = 256;
    const int N = in_sizes[0] / IN_C;   // 50000
    const int E = in_sizes[1] / 2;      // 800000
    const int* src = ei;
    const int* dst = ei + E;

    char* w = (char*)d_ws;
    size_t off = 0;
    auto alloc = [&](size_t bytes) { void* p = w + off; off = (off + bytes + 255) & ~255ull; return p; };
    __bf16*   h1u    = (__bf16*)alloc((size_t)(N + 1) * 128 * 2); // +sentinel row
    __bf16*   h2s    = (__bf16*)alloc((size_t)(N + 1) * 64 * 2);  // +sentinel row (zeroed by K1)
    unsigned* ebuf   = (unsigned*)alloc((size_t)P1_BLKS * P1_EPB * 4);   // 3.2 MB, block-contiguous
    int*      csr    = (int*)alloc((size_t)NBKT * CSR_CAP * 4);
    int2*     se     = (int2*)alloc((size_t)N * 8);
    float*    dinv   = (float*)alloc((size_t)(N + 1) * 4);        // +sentinel 0
    unsigned* gcnt2  = (unsigned*)alloc((size_t)P1_BLKS * NBKT * 4);
    unsigned* boffs2 = (unsigned*)alloc((size_t)P1_BLKS * NBKT * 4);
    __bf16*   wf1    = (__bf16*)alloc(64 * 64 * 8 * 2);
    __bf16*   wf2    = (__bf16*)alloc(16 * 64 * 8 * 2);

    // K1: P1 contiguous scatter (196) | wf1+wf2 pack (20) | sentinels (1)
    p1_pack_kernel<<<P1_BLKS + 20 + 1, TPB, 0, stream>>>(
        src, dst, E, gcnt2, boffs2, ebuf, W1, W2, wf1, wf2, dinv, h2s, N);

    // K2: CSR concat+build (196) | gemm1 (782, packed wf1)
    int gemmBlocks = cdiv(N, 64);                    // 782
    csr_gemm1_kernel<<<NBKT + gemmBlocks, TPB, 0, stream>>>(
        gcnt2, boffs2, ebuf, csr, se, dinv, N, x, (const bf16x8*)wf1, h1u);

    // K3: layer-1 aggregate (+bias, relu) fused with gemm2 -> h2s
    agg128_gemm2_kernel<<<cdiv(N, 16), TPB, 0, stream>>>(h1u, csr, se, dinv, b1,
                                                         (const bf16x8*)wf2, h2s, N);

    // K4: layer-2 aggregate -> d_out (fp32)
    agg64_kernel<<<cdiv((long)N * 64, TPB), TPB, 0, stream>>>(h2s, csr, se, dinv, b2,
                                                              (float*)d_out, N);
}